// Round 11
// baseline (42767.123 us; speedup 1.0000x reference)
//
#include <hip/hip_runtime.h>
#include <math.h>

// ESN recurrence: x_t = tanh(w_in*u_t + W x_{t-1}); out[t-washout] = c . x_t
// R11: column-partitioned, barrier-free wait->compute. Each thread owns 8
// x-elements (j = wave*512 + c*64 + lane) and FMAs them into ALL 8 rows from
// registers (no LDS x-staging, no stage barrier). Poll = 2-deep pipelined
// (two outstanding loads per pair, promote+reissue -> sampling period ~RTT/2).
// Producer publish = ONE coalesced 8-lane atomic store (64B line, replaces
// R9/R10's 8 same-line exchanges = RMW pileup). One barrier per step (psum).
// R10 regressed (37.8 vs R9 33.3): 8 per-chunk __syncthreads coupled all
// waves to every chunk's max arrival - sum of maxes. Reverted that.

#define H_   2048
#define RPB  8          // rows per block
#define NBLK 256
typedef unsigned long long ull;
// ws layout (float idx):
//   ull  [0,4096)       x pair buffers (= float [0,8192))
//   float [8192,10240)  c (scatter of w_out by mask)
//   float [10240, 10240+T*256)  part (per-step per-block partials)

__global__ void esn_zero(float* __restrict__ p, int n)
{
    int i = blockIdx.x * blockDim.x + threadIdx.x;
    int stride = gridDim.x * blockDim.x;
    for (; i < n; i += stride) p[i] = 0.0f;
}

__global__ __launch_bounds__(1024) void esn_scatter_c(const int* __restrict__ mask,
                                                      const float* __restrict__ w_out,
                                                      float* __restrict__ ws_f, int H)
{
    float* c = ws_f + 8192;
    for (int i = threadIdx.x; i < H; i += blockDim.x)
        atomicAdd(&c[mask[i]], w_out[i]);
}

__global__ __launch_bounds__(256) void esn_run(const float* __restrict__ u,
                                               const float* __restrict__ w_res,
                                               const float* __restrict__ w_in,
                                               float* __restrict__ out,
                                               float* __restrict__ ws_f,
                                               int T, int washout, int use_part)
{
    __shared__ float Wlds[RPB * H_];     // 64 KB, row-major
    __shared__ float psum[2][4][RPB];    // parity-double-buffered wave partials

    const int tid  = threadIdx.x;
    const int wave = tid >> 6;
    const int lane = tid & 63;
    const int bid  = blockIdx.x;
    const int grow = bid * RPB;
    const int jbase = (wave << 9) + lane;   // this thread's column base

    // ---- one-time: stage this block's 8 W rows into LDS (coalesced) ----
    {
        const float4* src = (const float4*)(w_res + (size_t)bid * RPB * H_);
        float4* dst = (float4*)Wlds;
        for (int i = tid; i < RPB * H_ / 4; i += 256) dst[i] = src[i];
    }
    float win_l = 0.f, c_l = 0.f;
    if (wave == 0 && lane < RPB) {
        win_l = w_in[grow + lane];
        c_l   = ws_f[8192 + grow + lane];
    }

    ull* pairs = (ull*)ws_f;
    float* part = ws_f + 10240;

    float u_next = u[0];
    __syncthreads();   // Wlds ready

    for (int k = 0; k < T; ++k) {
        const ull* sp = pairs + (k & 1) * H_ + jbase;
        ull*       dp = pairs + ((k + 1) & 1) * H_;
        float uk = u_next;
        if (k + 1 < T) u_next = u[k + 1];

        // ---- 2-deep pipelined poll of this thread's 8 pairs ----
        ull a[8], b[8];
#pragma unroll
        for (int c = 0; c < 8; ++c)
            a[c] = __hip_atomic_load(sp + (c << 6), __ATOMIC_RELAXED,
                                     __HIP_MEMORY_SCOPE_AGENT);
#pragma unroll
        for (int c = 0; c < 8; ++c)
            b[c] = __hip_atomic_load(sp + (c << 6), __ATOMIC_RELAXED,
                                     __HIP_MEMORY_SCOPE_AGENT);
        {
            int spins = 0;
            for (;;) {
                unsigned stale = 0;
#pragma unroll
                for (int c = 0; c < 8; ++c) {
                    if ((unsigned)(a[c] >> 32) != (unsigned)k) {
                        a[c] = b[c];   // promote the younger in-flight sample
                        b[c] = __hip_atomic_load(sp + (c << 6), __ATOMIC_RELAXED,
                                                 __HIP_MEMORY_SCOPE_AGENT);
                        stale = 1;
                    }
                }
                if (!stale) break;
                if (++spins > 1000000) break;   // failsafe
            }
        }

        // ---- thread-local: own 8 x-elems -> all 8 rows (no barrier) ----
        float4 a0 = {0.f,0.f,0.f,0.f}, a1 = {0.f,0.f,0.f,0.f};
#pragma unroll
        for (int c = 0; c < 8; ++c) {
            float xv = __uint_as_float((unsigned)a[c]);
            const float* wp = Wlds + (c << 6) + jbase;   // bank-conflict-free
            a0.x = fmaf(wp[0 * H_], xv, a0.x);
            a0.y = fmaf(wp[1 * H_], xv, a0.y);
            a0.z = fmaf(wp[2 * H_], xv, a0.z);
            a0.w = fmaf(wp[3 * H_], xv, a0.w);
            a1.x = fmaf(wp[4 * H_], xv, a1.x);
            a1.y = fmaf(wp[5 * H_], xv, a1.y);
            a1.z = fmaf(wp[6 * H_], xv, a1.z);
            a1.w = fmaf(wp[7 * H_], xv, a1.w);
        }
        // ---- intra-wave butterfly for all 8 rows ----
#pragma unroll
        for (int d = 1; d < 64; d <<= 1) {
            a0.x += __shfl_xor(a0.x, d); a0.y += __shfl_xor(a0.y, d);
            a0.z += __shfl_xor(a0.z, d); a0.w += __shfl_xor(a0.w, d);
            a1.x += __shfl_xor(a1.x, d); a1.y += __shfl_xor(a1.y, d);
            a1.z += __shfl_xor(a1.z, d); a1.w += __shfl_xor(a1.w, d);
        }
        if (lane == 0) {
            float* ps = psum[k & 1][wave];
            ps[0] = a0.x; ps[1] = a0.y; ps[2] = a0.z; ps[3] = a0.w;
            ps[4] = a1.x; ps[5] = a1.y; ps[6] = a1.z; ps[7] = a1.w;
        }
        __syncthreads();   // the ONE barrier per step

        // ---- wave 0, lanes 0-7: finish rows, tanh, coalesced publish ----
        if (wave == 0 && lane < RPB) {
            const int p = k & 1;
            float z = (psum[p][0][lane] + psum[p][1][lane]) +
                      (psum[p][2][lane] + psum[p][3][lane]);
            z = fmaf(win_l, uk, z);
            z = fminf(fmaxf(z, -15.f), 15.f);
            float e = __expf(2.f * z);
            float t = (e - 1.f) / (e + 1.f);
            ull pr = ((ull)(unsigned)(k + 1) << 32) | (ull)__float_as_uint(t);
            // 8 lanes, adjacent addresses, one 64B line -> one transaction
            __hip_atomic_store(dp + grow + lane, pr, __ATOMIC_RELAXED,
                               __HIP_MEMORY_SCOPE_AGENT);
            float po = c_l * t;
            po += __shfl_xor(po, 1);
            po += __shfl_xor(po, 2);
            po += __shfl_xor(po, 4);
            if (lane == 0) {
                if (use_part) part[(size_t)k * NBLK + bid] = po;
                else if (k >= washout) atomicAdd(&out[k - washout], po);
            }
        }
    }
}

__global__ __launch_bounds__(256) void esn_reduce(const float* __restrict__ part,
                                                  float* __restrict__ out,
                                                  int out_size, int washout)
{
    int wv = threadIdx.x >> 6, lane = threadIdx.x & 63;
    int t = blockIdx.x * 4 + wv;
    if (t >= out_size) return;
    const float4* p = (const float4*)(part + (size_t)(t + washout) * NBLK);
    float4 v = p[lane];
    float s = (v.x + v.y) + (v.z + v.w);
#pragma unroll
    for (int d = 1; d < 64; d <<= 1) s += __shfl_xor(s, d);
    if (lane == 0) out[t] = s;
}

extern "C" void kernel_launch(void* const* d_in, const int* in_sizes, int n_in,
                              void* d_out, int out_size, void* d_ws, size_t ws_size,
                              hipStream_t stream)
{
    const float* u     = (const float*)d_in[0];
    const float* w_res = (const float*)d_in[1];
    const float* w_in  = (const float*)d_in[2];
    const float* w_out = (const float*)d_in[3];
    const int*   mask  = (const int*)d_in[4];
    int T = in_sizes[0];
    int H = in_sizes[2];
    int washout = T - out_size;
    float* out  = (float*)d_out;
    float* ws_f = (float*)d_ws;

    size_t need = (size_t)(10240 + (size_t)T * NBLK) * 4;
    int use_part = (ws_size >= need) ? 1 : 0;

    hipLaunchKernelGGL(esn_zero, dim3(64), dim3(256), 0, stream, ws_f, 10240);
    if (!use_part)
        hipLaunchKernelGGL(esn_zero, dim3(32), dim3(256), 0, stream, out, out_size);
    hipLaunchKernelGGL(esn_scatter_c, dim3(1), dim3(1024), 0, stream, mask, w_out, ws_f, H);

    void* args[] = { (void*)&u, (void*)&w_res, (void*)&w_in, (void*)&out,
                     (void*)&ws_f, (void*)&T, (void*)&washout, (void*)&use_part };
    hipError_t e = hipLaunchCooperativeKernel((const void*)esn_run,
                                              dim3(NBLK), dim3(256),
                                              args, 0, stream);
    if (e != hipSuccess) {
        hipLaunchKernelGGL(esn_run, dim3(NBLK), dim3(256), 0, stream,
                           u, w_res, w_in, out, ws_f, T, washout, use_part);
    }
    if (use_part)
        hipLaunchKernelGGL(esn_reduce, dim3((out_size + 3) / 4), dim3(256), 0, stream,
                           ws_f + 10240, out, out_size, washout);
}

// Round 12
// 34346.710 us; speedup vs baseline: 1.2452x; 1.2452x over previous
//
#include <hip/hip_runtime.h>
#include <math.h>

// ESN recurrence: x_t = tanh(w_in*u_t + W x_{t-1}); out[t-washout] = c . x_t
// R12 = R9 backbone (wave-owns-2-rows, ds_read_b128 dot, batch-8 parallel
// poll of data-embedded epoch tags) + surgical shaves:
//  - 2-deep pipelined poll (promote+reissue): sampling period ~RTT/2
//  - lanes 0/1 parallel tanh + ONE 2-lane coalesced exchange per wave
//    (R9: lane 0 serial 2x tanh + 2 same-line RMWs x 4 waves = pileup)
//  - end barrier REMOVED (induction: staging k+1 requires observing all k+1
//    tags; any wave publishes k+1 only after its full step-k dot) ->
//    readout via per-wave fire-and-forget atomicAdd into pre-zeroed part
//  - stage barrier = s_waitcnt lgkmcnt(0) + s_barrier (no vmcnt(0) drain of
//    dead in-flight poll loads, which __syncthreads would force)
// R10 (-14%) and R11 (-28%) both perturbed the backbone and lost; reverted.

#define H_   2048
#define RPB  8          // rows per block
#define NBLK 256
typedef unsigned long long ull;
// ws layout (float idx):
//   ull  [0,4096)       x pair buffers (= float [0,8192))
//   float [8192,10240)  c (scatter of w_out by mask)
//   float [10240, 10240+T*256)  part (per-step per-block sums, atomicAdd)

__global__ void esn_zero(float* __restrict__ p, int n)
{
    int i = blockIdx.x * blockDim.x + threadIdx.x;
    int stride = gridDim.x * blockDim.x;
    for (; i < n; i += stride) p[i] = 0.0f;
}

__global__ __launch_bounds__(1024) void esn_scatter_c(const int* __restrict__ mask,
                                                      const float* __restrict__ w_out,
                                                      float* __restrict__ ws_f, int H)
{
    float* c = ws_f + 8192;
    for (int i = threadIdx.x; i < H; i += blockDim.x)
        atomicAdd(&c[mask[i]], w_out[i]);
}

__global__ __launch_bounds__(256) void esn_run(const float* __restrict__ u,
                                               const float* __restrict__ w_res,
                                               const float* __restrict__ w_in,
                                               float* __restrict__ out,
                                               float* __restrict__ ws_f,
                                               int T, int washout, int use_part)
{
    __shared__ float Wlds[RPB * H_];   // 64 KB
    __shared__ float xs[H_];           // 8 KB staged x_{t-1}

    const int tid  = threadIdx.x;
    const int wave = tid >> 6;
    const int lane = tid & 63;
    const int bid  = blockIdx.x;
    const int r0 = 2 * wave;
    const int myrow = bid * RPB + r0;   // wave's first row; lanes 0/1 own myrow+lane

    // ---- one-time: stage this block's 8 W rows into LDS (coalesced) ----
    {
        const float4* src = (const float4*)(w_res + (size_t)bid * RPB * H_);
        float4* dst = (float4*)Wlds;
        for (int i = tid; i < RPB * H_ / 4; i += 256) dst[i] = src[i];
    }
    float win_l = 0.f, c_l = 0.f;
    if (lane < 2) {
        win_l = w_in[myrow + lane];
        c_l   = ws_f[8192 + myrow + lane];
    }

    ull* pairs = (ull*)ws_f;
    float* part = ws_f + 10240;

    const float4* w0p = (const float4*)(Wlds + (r0)     * H_);
    const float4* w1p = (const float4*)(Wlds + (r0 + 1) * H_);
    const float4* xs4 = (const float4*)xs;

    float u_next = u[0];
    __syncthreads();   // Wlds ready

    for (int k = 0; k < T; ++k) {
        const ull* sp = pairs + (k & 1) * H_;
        ull*       dp = pairs + ((k + 1) & 1) * H_;
        float uk = u_next;
        if (k + 1 < T) u_next = u[k + 1];

        // ---- 2-deep pipelined poll of this thread's 8 pairs ----
        ull a[8], b[8];
#pragma unroll
        for (int i = 0; i < 8; ++i)
            a[i] = __hip_atomic_load(sp + (i << 8) + tid, __ATOMIC_RELAXED,
                                     __HIP_MEMORY_SCOPE_AGENT);
#pragma unroll
        for (int i = 0; i < 8; ++i)
            b[i] = __hip_atomic_load(sp + (i << 8) + tid, __ATOMIC_RELAXED,
                                     __HIP_MEMORY_SCOPE_AGENT);
        {
            int spins = 0;
            for (;;) {
                unsigned stale = 0;
#pragma unroll
                for (int i = 0; i < 8; ++i) {
                    if ((unsigned)(a[i] >> 32) != (unsigned)k) {
                        a[i] = b[i];   // promote younger in-flight sample
                        b[i] = __hip_atomic_load(sp + (i << 8) + tid,
                                                 __ATOMIC_RELAXED,
                                                 __HIP_MEMORY_SCOPE_AGENT);
                        stale = 1;
                    }
                }
                if (!stale) break;
                if (++spins > 1000000) break;   // failsafe
            }
        }
#pragma unroll
        for (int i = 0; i < 8; ++i)
            xs[(i << 8) + tid] = __uint_as_float((unsigned)a[i]);
        // stage barrier: drain LDS writes only (NOT the dead in-flight polls)
        asm volatile("s_waitcnt lgkmcnt(0)\n\ts_barrier" ::: "memory");

        // ---- dot: wave owns rows r0,r0+1; lanes sweep 2048 as float4 ----
        float4 a0 = {0.f,0.f,0.f,0.f}, a1 = {0.f,0.f,0.f,0.f};
#pragma unroll
        for (int c = 0; c < 8; ++c) {
            float4 xv  = xs4[(c << 6) + lane];
            float4 wv0 = w0p[(c << 6) + lane];
            float4 wv1 = w1p[(c << 6) + lane];
            a0.x = fmaf(wv0.x, xv.x, a0.x); a0.y = fmaf(wv0.y, xv.y, a0.y);
            a0.z = fmaf(wv0.z, xv.z, a0.z); a0.w = fmaf(wv0.w, xv.w, a0.w);
            a1.x = fmaf(wv1.x, xv.x, a1.x); a1.y = fmaf(wv1.y, xv.y, a1.y);
            a1.z = fmaf(wv1.z, xv.z, a1.z); a1.w = fmaf(wv1.w, xv.w, a1.w);
        }
        float s0 = (a0.x + a0.y) + (a0.z + a0.w);
        float s1 = (a1.x + a1.y) + (a1.z + a1.w);
#pragma unroll
        for (int d = 1; d < 64; d <<= 1) {
            s0 += __shfl_xor(s0, d);
            s1 += __shfl_xor(s1, d);
        }

        // ---- lanes 0,1: parallel tanh + one coalesced 2-lane publish ----
        if (lane < 2) {
            float z = fmaf(win_l, uk, (lane == 0) ? s0 : s1);
            z = fminf(fmaxf(z, -15.f), 15.f);
            float e = __expf(2.f * z);
            float t = (e - 1.f) / (e + 1.f);
            ull pr = ((ull)(unsigned)(k + 1) << 32) | (ull)__float_as_uint(t);
            (void)__hip_atomic_exchange(dp + myrow + lane, pr, __ATOMIC_RELAXED,
                                        __HIP_MEMORY_SCOPE_AGENT);
            // readout: per-wave fire-and-forget (part pre-zeroed)
            float po = c_l * t;
            po += __shfl_xor(po, 1);
            if (lane == 0 && k >= washout) {
                if (use_part) atomicAdd(&part[(size_t)k * NBLK + bid], po);
                else          atomicAdd(&out[k - washout], po);
            }
        }
        // NO end barrier: xs reuse safe by induction (see header comment)
    }
}

__global__ __launch_bounds__(256) void esn_reduce(const float* __restrict__ part,
                                                  float* __restrict__ out,
                                                  int out_size, int washout)
{
    int wv = threadIdx.x >> 6, lane = threadIdx.x & 63;
    int t = blockIdx.x * 4 + wv;
    if (t >= out_size) return;
    const float4* p = (const float4*)(part + (size_t)(t + washout) * NBLK);
    float4 v = p[lane];
    float s = (v.x + v.y) + (v.z + v.w);
#pragma unroll
    for (int d = 1; d < 64; d <<= 1) s += __shfl_xor(s, d);
    if (lane == 0) out[t] = s;
}

extern "C" void kernel_launch(void* const* d_in, const int* in_sizes, int n_in,
                              void* d_out, int out_size, void* d_ws, size_t ws_size,
                              hipStream_t stream)
{
    const float* u     = (const float*)d_in[0];
    const float* w_res = (const float*)d_in[1];
    const float* w_in  = (const float*)d_in[2];
    const float* w_out = (const float*)d_in[3];
    const int*   mask  = (const int*)d_in[4];
    int T = in_sizes[0];
    int H = in_sizes[2];
    int washout = T - out_size;
    float* out  = (float*)d_out;
    float* ws_f = (float*)d_ws;

    size_t need = (size_t)(10240 + (size_t)T * NBLK) * 4;
    int use_part = (ws_size >= need) ? 1 : 0;

    hipLaunchKernelGGL(esn_zero, dim3(64), dim3(256), 0, stream, ws_f, 10240);
    if (use_part)   // part is accumulated via atomicAdd -> must be zeroed
        hipLaunchKernelGGL(esn_zero, dim3(256), dim3(256), 0, stream,
                           ws_f + 10240, T * NBLK);
    else
        hipLaunchKernelGGL(esn_zero, dim3(32), dim3(256), 0, stream, out, out_size);
    hipLaunchKernelGGL(esn_scatter_c, dim3(1), dim3(1024), 0, stream, mask, w_out, ws_f, H);

    void* args[] = { (void*)&u, (void*)&w_res, (void*)&w_in, (void*)&out,
                     (void*)&ws_f, (void*)&T, (void*)&washout, (void*)&use_part };
    hipError_t e = hipLaunchCooperativeKernel((const void*)esn_run,
                                              dim3(NBLK), dim3(256),
                                              args, 0, stream);
    if (e != hipSuccess) {
        hipLaunchKernelGGL(esn_run, dim3(NBLK), dim3(256), 0, stream,
                           u, w_res, w_in, out, ws_f, T, washout, use_part);
    }
    if (use_part)
        hipLaunchKernelGGL(esn_reduce, dim3((out_size + 3) / 4), dim3(256), 0, stream,
                           ws_f + 10240, out, out_size, washout);
}

// Round 13
// 34257.455 us; speedup vs baseline: 1.2484x; 1.0026x over previous
//
#include <hip/hip_runtime.h>
#include <math.h>

// ESN recurrence: x_t = tanh(w_in*u_t + W x_{t-1}); out[t-washout] = c . x_t
// R13: 128 blocks x 512 threads, 16 rows/block. Halves sync participants
// (arrivals, pollers, straggler population, IC poll burst) and doubles
// occupancy (8 waves/CU). Backbone = R9: wave-owns-2-rows ds_read_b128 dot,
// data-embedded epoch tags (8B pair = value|epoch), 2-deep pipelined poll
// (now 4 pairs/thread), lanes-0/1 tanh + one 2-lane coalesced exchange.
// End barrier RESTORED (raw s_barrier): R12's no-barrier induction was
// UNSOUND - remote tags at k+1 prove all blocks published k, not that my
// own slowest wave finished reading xs for step k. Races intra-block.
// W: 16 rows x 8KB = 128KB LDS + 8KB xs = 136KB (<160KB, 1 block/CU).

#define H_   2048
#define RPB  16         // rows per block
#define NBLK 128
#define NTHR 512
typedef unsigned long long ull;
// ws layout (float idx):
//   ull  [0,4096)       x pair buffers (= float [0,8192))
//   float [8192,10240)  c (scatter of w_out by mask)
//   float [10240, 10240+T*128)  part (per-step per-block sums, atomicAdd)

__global__ void esn_zero(float* __restrict__ p, int n)
{
    int i = blockIdx.x * blockDim.x + threadIdx.x;
    int stride = gridDim.x * blockDim.x;
    for (; i < n; i += stride) p[i] = 0.0f;
}

__global__ __launch_bounds__(1024) void esn_scatter_c(const int* __restrict__ mask,
                                                      const float* __restrict__ w_out,
                                                      float* __restrict__ ws_f, int H)
{
    float* c = ws_f + 8192;
    for (int i = threadIdx.x; i < H; i += blockDim.x)
        atomicAdd(&c[mask[i]], w_out[i]);
}

__global__ __launch_bounds__(NTHR) void esn_run(const float* __restrict__ u,
                                                const float* __restrict__ w_res,
                                                const float* __restrict__ w_in,
                                                float* __restrict__ out,
                                                float* __restrict__ ws_f,
                                                int T, int washout, int use_part)
{
    __shared__ float Wlds[RPB * H_];   // 128 KB
    __shared__ float xs[H_];           // 8 KB staged x_{t-1}

    const int tid  = threadIdx.x;
    const int wave = tid >> 6;         // 0..7
    const int lane = tid & 63;
    const int bid  = blockIdx.x;
    const int r0 = 2 * wave;
    const int myrow = bid * RPB + r0;  // wave's first row; lanes 0/1 own myrow+lane

    // ---- one-time: stage this block's 16 W rows into LDS (coalesced) ----
    {
        const float4* src = (const float4*)(w_res + (size_t)bid * RPB * H_);
        float4* dst = (float4*)Wlds;
        for (int i = tid; i < RPB * H_ / 4; i += NTHR) dst[i] = src[i];
    }
    float win_l = 0.f, c_l = 0.f;
    if (lane < 2) {
        win_l = w_in[myrow + lane];
        c_l   = ws_f[8192 + myrow + lane];
    }

    ull* pairs = (ull*)ws_f;
    float* part = ws_f + 10240;

    const float4* w0p = (const float4*)(Wlds + (r0)     * H_);
    const float4* w1p = (const float4*)(Wlds + (r0 + 1) * H_);
    const float4* xs4 = (const float4*)xs;

    float u_next = u[0];
    __syncthreads();   // Wlds ready

    for (int k = 0; k < T; ++k) {
        const ull* sp = pairs + (k & 1) * H_;
        ull*       dp = pairs + ((k + 1) & 1) * H_;
        float uk = u_next;
        if (k + 1 < T) u_next = u[k + 1];

        // ---- 2-deep pipelined poll of this thread's 4 pairs ----
        ull a[4], b[4];
#pragma unroll
        for (int i = 0; i < 4; ++i)
            a[i] = __hip_atomic_load(sp + (i << 9) + tid, __ATOMIC_RELAXED,
                                     __HIP_MEMORY_SCOPE_AGENT);
#pragma unroll
        for (int i = 0; i < 4; ++i)
            b[i] = __hip_atomic_load(sp + (i << 9) + tid, __ATOMIC_RELAXED,
                                     __HIP_MEMORY_SCOPE_AGENT);
        {
            int spins = 0;
            for (;;) {
                unsigned stale = 0;
#pragma unroll
                for (int i = 0; i < 4; ++i) {
                    if ((unsigned)(a[i] >> 32) != (unsigned)k) {
                        a[i] = b[i];   // promote younger in-flight sample
                        b[i] = __hip_atomic_load(sp + (i << 9) + tid,
                                                 __ATOMIC_RELAXED,
                                                 __HIP_MEMORY_SCOPE_AGENT);
                        stale = 1;
                    }
                }
                if (!stale) break;
                if (++spins > 1000000) break;   // failsafe
            }
        }
#pragma unroll
        for (int i = 0; i < 4; ++i)
            xs[(i << 9) + tid] = __uint_as_float((unsigned)a[i]);
        // stage barrier: drain LDS writes only (not dead in-flight polls)
        asm volatile("s_waitcnt lgkmcnt(0)\n\ts_barrier" ::: "memory");

        // ---- dot: wave owns rows r0,r0+1; lanes sweep 2048 as float4 ----
        float4 a0 = {0.f,0.f,0.f,0.f}, a1 = {0.f,0.f,0.f,0.f};
#pragma unroll
        for (int c = 0; c < 8; ++c) {
            float4 xv  = xs4[(c << 6) + lane];
            float4 wv0 = w0p[(c << 6) + lane];
            float4 wv1 = w1p[(c << 6) + lane];
            a0.x = fmaf(wv0.x, xv.x, a0.x); a0.y = fmaf(wv0.y, xv.y, a0.y);
            a0.z = fmaf(wv0.z, xv.z, a0.z); a0.w = fmaf(wv0.w, xv.w, a0.w);
            a1.x = fmaf(wv1.x, xv.x, a1.x); a1.y = fmaf(wv1.y, xv.y, a1.y);
            a1.z = fmaf(wv1.z, xv.z, a1.z); a1.w = fmaf(wv1.w, xv.w, a1.w);
        }
        float s0 = (a0.x + a0.y) + (a0.z + a0.w);
        float s1 = (a1.x + a1.y) + (a1.z + a1.w);
#pragma unroll
        for (int d = 1; d < 64; d <<= 1) {
            s0 += __shfl_xor(s0, d);
            s1 += __shfl_xor(s1, d);
        }

        // ---- lanes 0,1: parallel tanh + one coalesced 2-lane publish ----
        if (lane < 2) {
            float z = fmaf(win_l, uk, (lane == 0) ? s0 : s1);
            z = fminf(fmaxf(z, -15.f), 15.f);
            float e = __expf(2.f * z);
            float t = (e - 1.f) / (e + 1.f);
            ull pr = ((ull)(unsigned)(k + 1) << 32) | (ull)__float_as_uint(t);
            (void)__hip_atomic_exchange(dp + myrow + lane, pr, __ATOMIC_RELAXED,
                                        __HIP_MEMORY_SCOPE_AGENT);
            // readout: per-wave fire-and-forget (part pre-zeroed)
            float po = c_l * t;
            po += __shfl_xor(po, 1);
            if (lane == 0 && k >= washout) {
                if (use_part) atomicAdd(&part[(size_t)k * NBLK + bid], po);
                else          atomicAdd(&out[k - washout], po);
            }
        }
        // end barrier: no thread restages xs until all waves' dots are done.
        // (each wave's xs reads are data-complete before its publish; no
        // vmcnt drain needed -> raw s_barrier, not __syncthreads)
        asm volatile("s_barrier" ::: "memory");
    }
}

// sum the 128 per-block partials for each output step (one wave per t)
__global__ __launch_bounds__(256) void esn_reduce(const float* __restrict__ part,
                                                  float* __restrict__ out,
                                                  int out_size, int washout)
{
    int wv = threadIdx.x >> 6, lane = threadIdx.x & 63;
    int t = blockIdx.x * 4 + wv;
    if (t >= out_size) return;
    const float4* p = (const float4*)(part + (size_t)(t + washout) * NBLK);
    float s = 0.f;
    if (lane < 32) {
        float4 v = p[lane];
        s = (v.x + v.y) + (v.z + v.w);
    }
#pragma unroll
    for (int d = 1; d < 64; d <<= 1) s += __shfl_xor(s, d);
    if (lane == 0) out[t] = s;
}

extern "C" void kernel_launch(void* const* d_in, const int* in_sizes, int n_in,
                              void* d_out, int out_size, void* d_ws, size_t ws_size,
                              hipStream_t stream)
{
    const float* u     = (const float*)d_in[0];
    const float* w_res = (const float*)d_in[1];
    const float* w_in  = (const float*)d_in[2];
    const float* w_out = (const float*)d_in[3];
    const int*   mask  = (const int*)d_in[4];
    int T = in_sizes[0];
    int H = in_sizes[2];
    int washout = T - out_size;
    float* out  = (float*)d_out;
    float* ws_f = (float*)d_ws;

    size_t need = (size_t)(10240 + (size_t)T * NBLK) * 4;
    int use_part = (ws_size >= need) ? 1 : 0;

    hipLaunchKernelGGL(esn_zero, dim3(64), dim3(256), 0, stream, ws_f, 10240);
    if (use_part)   // part is accumulated via atomicAdd -> must be zeroed
        hipLaunchKernelGGL(esn_zero, dim3(256), dim3(256), 0, stream,
                           ws_f + 10240, T * NBLK);
    else
        hipLaunchKernelGGL(esn_zero, dim3(32), dim3(256), 0, stream, out, out_size);
    hipLaunchKernelGGL(esn_scatter_c, dim3(1), dim3(1024), 0, stream, mask, w_out, ws_f, H);

    void* args[] = { (void*)&u, (void*)&w_res, (void*)&w_in, (void*)&out,
                     (void*)&ws_f, (void*)&T, (void*)&washout, (void*)&use_part };
    hipError_t e = hipLaunchCooperativeKernel((const void*)esn_run,
                                              dim3(NBLK), dim3(NTHR),
                                              args, 0, stream);
    if (e != hipSuccess) {
        hipLaunchKernelGGL(esn_run, dim3(NBLK), dim3(NTHR), 0, stream,
                           u, w_res, w_in, out, ws_f, T, washout, use_part);
    }
    if (use_part)
        hipLaunchKernelGGL(esn_reduce, dim3((out_size + 3) / 4), dim3(256), 0, stream,
                           ws_f + 10240, out, out_size, washout);
}

// Round 14
// 33293.240 us; speedup vs baseline: 1.2846x; 1.0290x over previous
//
#include <hip/hip_runtime.h>
#include <math.h>

// ESN recurrence: x_t = tanh(w_in*u_t + W x_{t-1}); out[t-washout] = c . x_t
// R14 = R9's esn_run VERBATIM (the measured optimum: 33.28-33.30 ms rows),
// probe removed, epilogue trimmed. Four rounds of perturbations (R10 chunked
// barriers -14%, R11 column partition -28%, R12 shaves -3%, R13 pop/occupancy
// null) bracket R9 as the local optimum:
//  - data-embedded epoch tags (8B pair = value|epoch), stores ARE the sync
//  - single-deep batch-8 parallel poll (2-deep doubled IC traffic, lost)
//  - wave-owns-2-rows ds_read_b128 dot, 64-lane butterfly
//  - lane-0 tanh + 2 exchanges (commit at far unit), plain part store
//  - two __syncthreads per step (stage, psum) -- measured cost ~nothing
// Plateau evidence: per-step ~4.1us invariant to sync mechanism, fences,
// RMWs, participants (256 vs 128), occupancy (4 vs 8 waves/CU), poll depth.

#define H_   2048
#define RPB  8          // rows per block
#define NBLK 256
typedef unsigned long long ull;
// ws layout (float idx):
//   ull  [0,4096)       x pair buffers (= float [0,8192))
//   float [8192,10240)  c (scatter of w_out by mask)
//   float [10240, 10240+T*256)  part (per-step per-block partials, plain store)

__global__ void esn_zero(float* __restrict__ p, int n)
{
    int i = blockIdx.x * blockDim.x + threadIdx.x;
    int stride = gridDim.x * blockDim.x;
    for (; i < n; i += stride) p[i] = 0.0f;
}

__global__ __launch_bounds__(1024) void esn_scatter_c(const int* __restrict__ mask,
                                                      const float* __restrict__ w_out,
                                                      float* __restrict__ ws_f, int H)
{
    float* c = ws_f + 8192;
    for (int i = threadIdx.x; i < H; i += blockDim.x)
        atomicAdd(&c[mask[i]], w_out[i]);
}

__global__ __launch_bounds__(256) void esn_run(const float* __restrict__ u,
                                               const float* __restrict__ w_res,
                                               const float* __restrict__ w_in,
                                               float* __restrict__ out,
                                               float* __restrict__ ws_f,
                                               int T, int washout, int use_part)
{
    __shared__ float Wlds[RPB * H_];   // 64 KB
    __shared__ float xs[H_];
    __shared__ float psum[4];

    const int tid  = threadIdx.x;
    const int wave = tid >> 6;
    const int lane = tid & 63;
    const int bid  = blockIdx.x;
    const int r0 = 2 * wave, r1 = 2 * wave + 1;
    const int grow0 = bid * RPB + r0, grow1 = bid * RPB + r1;

    {
        const float4* src = (const float4*)(w_res + (size_t)bid * RPB * H_);
        float4* dst = (float4*)Wlds;
        for (int i = tid; i < RPB * H_ / 4; i += 256) dst[i] = src[i];
    }
    float win0 = 0.f, win1 = 0.f, c0 = 0.f, c1 = 0.f;
    if (lane == 0) {
        win0 = w_in[grow0]; win1 = w_in[grow1];
        c0 = ws_f[8192 + grow0]; c1 = ws_f[8192 + grow1];
    }

    ull* pairs = (ull*)ws_f;
    float* part = ws_f + 10240;

    const float4* w0p = (const float4*)(Wlds + r0 * H_);
    const float4* w1p = (const float4*)(Wlds + (r0 + 1) * H_);
    const float4* xs4 = (const float4*)xs;

    float u_next = u[0];
    __syncthreads();   // Wlds ready

    for (int k = 0; k < T; ++k) {
        const ull* sp = pairs + (k & 1) * H_;
        ull*       dp = pairs + ((k + 1) & 1) * H_;
        float uk = u_next;
        if (k + 1 < T) u_next = u[k + 1];

        // ---- stage x_k: batch load, then PARALLEL-retry sweeps ----
        ull pv[8];
#pragma unroll
        for (int i = 0; i < 8; ++i)
            pv[i] = __hip_atomic_load(sp + (i << 8) + tid, __ATOMIC_RELAXED,
                                      __HIP_MEMORY_SCOPE_AGENT);
        {
            int spins = 0;
            for (;;) {
                unsigned pend = 0;
#pragma unroll
                for (int i = 0; i < 8; ++i)
                    if ((unsigned)(pv[i] >> 32) != (unsigned)k) {
                        pv[i] = __hip_atomic_load(sp + (i << 8) + tid,
                                                  __ATOMIC_RELAXED,
                                                  __HIP_MEMORY_SCOPE_AGENT);
                        pend = 1;
                    }
                if (!pend) break;
                if (++spins > 500000) break; // failsafe
            }
        }
#pragma unroll
        for (int i = 0; i < 8; ++i)
            xs[(i << 8) + tid] = __uint_as_float((unsigned)pv[i]);
        __syncthreads();

        // ---- dot: wave owns rows r0,r0+1 ----
        float4 a0 = {0.f,0.f,0.f,0.f}, a1 = {0.f,0.f,0.f,0.f};
#pragma unroll
        for (int c = 0; c < 8; ++c) {
            float4 xv  = xs4[c * 64 + lane];
            float4 wv0 = w0p[c * 64 + lane];
            float4 wv1 = w1p[c * 64 + lane];
            a0.x = fmaf(wv0.x, xv.x, a0.x); a0.y = fmaf(wv0.y, xv.y, a0.y);
            a0.z = fmaf(wv0.z, xv.z, a0.z); a0.w = fmaf(wv0.w, xv.w, a0.w);
            a1.x = fmaf(wv1.x, xv.x, a1.x); a1.y = fmaf(wv1.y, xv.y, a1.y);
            a1.z = fmaf(wv1.z, xv.z, a1.z); a1.w = fmaf(wv1.w, xv.w, a1.w);
        }
        float s0 = (a0.x + a0.y) + (a0.z + a0.w);
        float s1 = (a1.x + a1.y) + (a1.z + a1.w);
#pragma unroll
        for (int d = 1; d < 64; d <<= 1) {
            s0 += __shfl_xor(s0, d);
            s1 += __shfl_xor(s1, d);
        }

        if (lane == 0) {
            float z0 = fmaf(win0, uk, s0);
            float z1 = fmaf(win1, uk, s1);
            z0 = fminf(fmaxf(z0, -15.f), 15.f);
            z1 = fminf(fmaxf(z1, -15.f), 15.f);
            float e0 = __expf(2.f * z0), e1 = __expf(2.f * z1);
            float t0 = (e0 - 1.f) / (e0 + 1.f), t1 = (e1 - 1.f) / (e1 + 1.f);
            ull p0 = ((ull)(unsigned)(k + 1) << 32) | (ull)__float_as_uint(t0);
            ull p1 = ((ull)(unsigned)(k + 1) << 32) | (ull)__float_as_uint(t1);
            // exchange: commits at the far unit (no writeback lag)
            (void)__hip_atomic_exchange(dp + grow0, p0, __ATOMIC_RELAXED,
                                        __HIP_MEMORY_SCOPE_AGENT);
            (void)__hip_atomic_exchange(dp + grow1, p1, __ATOMIC_RELAXED,
                                        __HIP_MEMORY_SCOPE_AGENT);
            psum[wave] = c0 * t0 + c1 * t1;
        }
        __syncthreads();   // psum ready; xs reads done (safe to restage)

        if (tid == 0) {
            float pw = (psum[0] + psum[1]) + (psum[2] + psum[3]);
            if (use_part) part[(size_t)k * NBLK + bid] = pw;
            else if (k >= washout) atomicAdd(&out[k - washout], pw);
        }
    }
}

__global__ __launch_bounds__(256) void esn_reduce(const float* __restrict__ part,
                                                  float* __restrict__ out,
                                                  int out_size, int washout)
{
    int wv = threadIdx.x >> 6, lane = threadIdx.x & 63;
    int t = blockIdx.x * 4 + wv;
    if (t >= out_size) return;
    const float4* p = (const float4*)(part + (size_t)(t + washout) * NBLK);
    float4 v = p[lane];
    float s = (v.x + v.y) + (v.z + v.w);
#pragma unroll
    for (int d = 1; d < 64; d <<= 1) s += __shfl_xor(s, d);
    if (lane == 0) out[t] = s;
}

extern "C" void kernel_launch(void* const* d_in, const int* in_sizes, int n_in,
                              void* d_out, int out_size, void* d_ws, size_t ws_size,
                              hipStream_t stream)
{
    const float* u     = (const float*)d_in[0];
    const float* w_res = (const float*)d_in[1];
    const float* w_in  = (const float*)d_in[2];
    const float* w_out = (const float*)d_in[3];
    const int*   mask  = (const int*)d_in[4];
    int T = in_sizes[0];
    int H = in_sizes[2];
    int washout = T - out_size;
    float* out  = (float*)d_out;
    float* ws_f = (float*)d_ws;

    size_t need = (size_t)(10240 + (size_t)T * NBLK) * 4;
    int use_part = (ws_size >= need) ? 1 : 0;

    hipLaunchKernelGGL(esn_zero, dim3(64), dim3(256), 0, stream, ws_f, 10240);
    if (!use_part)   // direct-atomic fallback needs out pre-zeroed
        hipLaunchKernelGGL(esn_zero, dim3(32), dim3(256), 0, stream, out, out_size);
    hipLaunchKernelGGL(esn_scatter_c, dim3(1), dim3(1024), 0, stream, mask, w_out, ws_f, H);

    void* args[] = { (void*)&u, (void*)&w_res, (void*)&w_in, (void*)&out,
                     (void*)&ws_f, (void*)&T, (void*)&washout, (void*)&use_part };
    hipError_t e = hipLaunchCooperativeKernel((const void*)esn_run,
                                              dim3(NBLK), dim3(256),
                                              args, 0, stream);
    if (e != hipSuccess) {
        hipLaunchKernelGGL(esn_run, dim3(NBLK), dim3(256), 0, stream,
                           u, w_res, w_in, out, ws_f, T, washout, use_part);
    }
    if (use_part)
        hipLaunchKernelGGL(esn_reduce, dim3((out_size + 3) / 4), dim3(256), 0, stream,
                           ws_f + 10240, out, out_size, washout);
}